// Round 11
// baseline (278.422 us; speedup 1.0000x reference)
//
#include <hip/hip_runtime.h>
#include <math.h>

#define NB 8
#define NA 720
#define NPAIR 360
#define ND 1024
#define NH 512
#define NW 512

// DS = 4/1024 -> 1/DS = 256. S0 = -2 + DS/2 -> -S0/DS = 511.5
#define DXF 0.00390625f
#define IMG_MIN_F (-1.0f)
#define DTH_D (3.14159265358979323846 / 720.0)

#define TI 32            // table tile: 32 top rows (bp blocks use 16-row halves)
#define TJ 32            // table tile: 32 cols
#define WIN 128          // table clamp constant (kept from R9; bp windows are 64 elems)

typedef unsigned int uint32;
typedef __fp16 half2v __attribute__((ext_vector_type(2)));   // matches cvt_pkrtz return

// ---------------- Kernel 1: 11-tap conv on angle PAIR (p, 719-p) -> interleaved f16 G2 ----
// G2[b][p][d] (uint2): .x = pack(y_p[d], y_p[d+1]) f16x2 ; .y = same for row 719-p.
__global__ __launch_bounds__(256) void conv_kernel(const float* __restrict__ x,
                                                   const float* __restrict__ w,
                                                   uint2* __restrict__ G2) {
    int id = blockIdx.x;                  // b*360 + p
    int b = id / NPAIR;
    int p = id - b * NPAIR;
    const float* xr0 = x + ((size_t)b * NA + p) * ND;
    const float* xr1 = x + ((size_t)b * NA + (719 - p)) * ND;

    __shared__ float s[2][16 + ND];
    __shared__ unsigned short hh[2][ND + 8];
    __shared__ float wk[16];

    int tid = threadIdx.x;                // 256 threads
    if (tid < 16) { s[0][tid] = 0.0f; s[1][tid] = 0.0f; }
    if (tid < 11) wk[tid] = w[tid] * (float)DTH_D;
    if (tid < 8)  { hh[0][ND + tid] = 0; hh[1][ND + tid] = 0; }

    *(float4*)&s[0][16 + tid * 4] = ((const float4*)xr0)[tid];
    *(float4*)&s[1][16 + tid * 4] = ((const float4*)xr1)[tid];
    __syncthreads();

    int d0 = tid * 4;
#pragma unroll
    for (int r = 0; r < 2; ++r) {
        float o0 = 0.f, o1 = 0.f, o2 = 0.f, o3 = 0.f;
#pragma unroll
        for (int k = 0; k < 11; ++k) {
            float wv = wk[k];
            o0 = fmaf(wv, s[r][6 + d0 + k], o0);
            o1 = fmaf(wv, s[r][7 + d0 + k], o1);
            o2 = fmaf(wv, s[r][8 + d0 + k], o2);
            o3 = fmaf(wv, s[r][9 + d0 + k], o3);
        }
        union { _Float16 h[4]; uint2 u2; } pk;
        pk.h[0] = (_Float16)o0; pk.h[1] = (_Float16)o1;
        pk.h[2] = (_Float16)o2; pk.h[3] = (_Float16)o3;
        *(uint2*)&hh[r][d0] = pk.u2;      // 8B-aligned (2*d0 = 8*tid)
    }
    __syncthreads();

    uint32 a0 = *(const uint32*)&hh[0][d0];
    uint32 a1 = *(const uint32*)&hh[0][d0 + 2];
    uint32 a2 = *(const uint32*)&hh[0][d0 + 4];
    uint32 c0 = *(const uint32*)&hh[1][d0];
    uint32 c1 = *(const uint32*)&hh[1][d0 + 2];
    uint32 c2 = *(const uint32*)&hh[1][d0 + 4];

    uint2* gout = G2 + ((size_t)b * NPAIR + p) * ND + d0;
    gout[0] = make_uint2(a0, c0);
    gout[1] = make_uint2((a0 >> 16) | (a1 << 16), (c0 >> 16) | (c1 << 16));
    gout[2] = make_uint2(a1, c1);
    gout[3] = make_uint2((a1 >> 16) | (a2 << 16), (c1 >> 16) | (c2 << 16));
}

// ---------------- Kernel 2: fused per-(tile,pair) table: (ca, sa, 511.5-b1, 511.5-b2) ----
__global__ __launch_bounds__(256) void table_kernel(float4* __restrict__ tpr) {
    int idx = blockIdx.x * 256 + threadIdx.x;   // 360 pairs * 128 tiles = 46080
    if (idx >= NPAIR * 128) return;
    int p = idx >> 7;
    int t = idx & 127;
    float th = (float)((p + 0.5) * DTH_D);      // THETAS f64->f32 like reference
    double thd = (double)th;
    float ca = (float)(cos(thd) * 256.0);
    float sa = (float)(sin(thd) * 256.0);

    int it = t >> 4, jt = t & 15;
    int ibase = it * TI, jbase = jt * TJ;
    float pi_lo = IMG_MIN_F + (ibase + 0.5f) * DXF;
    float pi_hi = IMG_MIN_F + (ibase + TI - 0.5f) * DXF;
    float pj_lo = IMG_MIN_F + (jbase + 0.5f) * DXF;
    float pj_hi = IMG_MIN_F + (jbase + TJ - 0.5f) * DXF;
    float sj = fminf(pj_lo * sa, pj_hi * sa);
    float umin1 = 511.5f + fminf(pi_lo * ca, pi_hi * ca) + sj;
    float umin2 = 511.5f + fminf(-pi_lo * ca, -pi_hi * ca) + sj;
    int b1 = ((int)floorf(umin1) - 1) & ~3;     // 4-elem align -> 32B align in G2
    int b2 = ((int)floorf(umin2) - 1) & ~3;
    b1 = max(0, min(b1, ND - WIN));
    b2 = max(0, min(b2, ND - WIN));
    tpr[(size_t)t * NPAIR + p] =
        make_float4(ca, sa, 511.5f - (float)b1, 511.5f - (float)b2);
}

// ---------------- Kernel 3: backprojection, 4-wave blocks, split-source DMA windows -----
// 2048 blocks (8/CU, 32 waves/CU): block = 16 top rows x 32 cols (+16 mirror rows).
// Per chunk: 8 pairs; wave wv stages pairs (c*8+2wv, c*8+2wv+1), one DMA each:
// lanes 0-31 -> 64-elem window W1 (u1 range), lanes 32-63 -> W2 (u2 range).
// One u-sample = one ds_read_b64 + v_dot2_f32_f16 per packed row.

__device__ __forceinline__ void async_ld16(const float* g, float* l) {
    __builtin_amdgcn_global_load_lds((const __attribute__((address_space(1))) void*)g,
                                     (__attribute__((address_space(3))) void*)l,
                                     16, 0, 0);
}

#define WAIT_VM0_BARRIER() do { \
    asm volatile("" ::: "memory"); \
    __builtin_amdgcn_s_waitcnt(0x0F70); /* vmcnt(0) only */ \
    __builtin_amdgcn_s_barrier(); \
    asm volatile("" ::: "memory"); \
} while (0)

// acc(f32) += taps.lo16 * gf.lo + taps.hi16 * gf.hi   (one VOP3P dot2)
#define DOT2(acc_, taps_, gf_) \
    asm("v_dot2_f32_f16 %0, %1, %2, %0" : "+v"(acc_) : "v"(taps_), "v"(gf_))

__global__ __launch_bounds__(256, 8) void bp_kernel(const uint2* __restrict__ G2,
                                                    const float4* __restrict__ tpr,
                                                    float* __restrict__ out) {
    int bid = blockIdx.x;
    // XCD-chunked swizzle (2048 = 8*256, bijective): XCD x -> all 256 blocks of batch x
    int lb = (bid & 7) * 256 + (bid >> 3);
    int b = lb >> 8;             // batch 0..7
    int t16 = lb & 255;          // 16-row x 32-col half-tile id
    int it16 = t16 >> 4;         // 0..15 over top-half rows
    int jt = t16 & 15;
    int ibase = it16 * 16, jbase = jt * 32;
    int tile32 = (it16 >> 1) * 16 + jt;      // table tile (32x32)

    int tid = threadIdx.x;
    int lane = tid & 63;
    int wv = tid >> 6;           // 0..3
    int jj = lane & 31;
    int hi = lane >> 5;          // 0/1 -> +1 row

    int j = jbase + jj;
    float pxj = IMG_MIN_F + (j + 0.5f) * DXF;
    int i0 = ibase + 2 * wv + hi;           // +8*r, r=0..1
    float pxi = IMG_MIN_F + (i0 + 0.5f) * DXF;

    __shared__ __align__(16) uint2 buf[2][8][128];   // 2*8*128*8 = 16384 B (W1|W2 per pair)

    const uint2* gp = G2 + (size_t)b * (NPAIR * ND);
    const float4* tp = tpr + (size_t)tile32 * NPAIR;

    float accT0 = 0.f, accT1 = 0.f;         // pixels (i0, j), (i0+8, j)
    float accM0 = 0.f, accM1 = 0.f;         // mirrors (511-i0, j), (511-i0-8, j)

#define STAGE(c_, bs_) do { \
    _Pragma("unroll") \
    for (int q_ = 0; q_ < 2; ++q_) { \
        int p_ = (c_) * 8 + 2 * wv + q_; \
        float4 t4_ = tp[p_]; \
        int b1_ = (int)(511.5f - t4_.z); \
        int b2_ = (int)(511.5f - t4_.w); \
        const float* gA_ = (const float*)(gp + (size_t)p_ * ND + b1_) + jj * 4; \
        const float* gB_ = (const float*)(gp + (size_t)p_ * ND + b2_) + jj * 4; \
        const float* gs_ = hi ? gB_ : gA_; \
        async_ld16(gs_, (float*)&buf[bs_][2 * wv + q_][0]); \
    } \
} while (0)

    STAGE(0, 0);
    WAIT_VM0_BARRIER();

    for (int c = 0; c < 45; ++c) {
        int cur = c & 1;
        if (c + 1 < 45) STAGE(c + 1, cur ^ 1);   // 2 async DMAs per wave, no VALU tail
#pragma unroll
        for (int k = 0; k < 8; ++k) {
            int p = c * 8 + k;
            float4 t4 = tp[p];                 // uniform -> s_load_dwordx4
            float du = t4.x * (8.0f * DXF);
            float u1 = fmaf(pxj, t4.y, fmaf(pxi, t4.x, t4.z));    // local in W1
            float u2 = fmaf(pxj, t4.y, fmaf(pxi, -t4.x, t4.w));   // local in W2
            const uint2* W1 = &buf[cur][k][0];
            const uint2* W2 = W1 + 64;
#pragma unroll
            for (int r = 0; r < 2; ++r) {
                // ---- u1: .x = row p -> T, .y = row 719-p -> M
                int iu1 = (int)u1;                    // u1 in [1,50): trunc == floor
                float f1 = __builtin_amdgcn_fractf(u1);
                half2v pk1 = __builtin_amdgcn_cvt_pkrtz(1.0f - f1, f1);
                uint2 q1 = W1[iu1];                   // one ds_read_b64
                if (r == 0) { DOT2(accT0, q1.x, pk1); DOT2(accM0, q1.y, pk1); }
                else        { DOT2(accT1, q1.x, pk1); DOT2(accM1, q1.y, pk1); }

                // ---- u2: .x = row p -> M, .y = row 719-p -> T
                int iu2 = (int)u2;
                float f2 = __builtin_amdgcn_fractf(u2);
                half2v pk2 = __builtin_amdgcn_cvt_pkrtz(1.0f - f2, f2);
                uint2 q2 = W2[iu2];                   // one ds_read_b64
                if (r == 0) { DOT2(accM0, q2.x, pk2); DOT2(accT0, q2.y, pk2); }
                else        { DOT2(accM1, q2.x, pk2); DOT2(accT1, q2.y, pk2); }

                u1 += du;
                u2 -= du;
            }
        }
        WAIT_VM0_BARRIER();                    // drain this chunk's DMAs, swap buffers
    }

    float* orow = out + (size_t)b * (NH * NW);
    {
        int i = i0;
        orow[i * NW + j] = accT0;
        orow[(511 - i) * NW + j] = accM0;
        i = i0 + 8;
        orow[i * NW + j] = accT1;
        orow[(511 - i) * NW + j] = accM1;
    }
#undef STAGE
}

extern "C" void kernel_launch(void* const* d_in, const int* in_sizes, int n_in,
                              void* d_out, int out_size, void* d_ws, size_t ws_size,
                              hipStream_t stream) {
    const float* x = (const float*)d_in[0];      // [8,1,720,1024] f32
    const float* w = (const float*)d_in[1];      // [1,1,1,11] f32
    float* out = (float*)d_out;                  // [8,1,512,512] f32

    uint2* G2 = (uint2*)d_ws;                    // 8*360*1024*8 B = 23.6 MB
    float4* tpr = (float4*)((float*)d_ws + (size_t)NB * NPAIR * ND * 2);  // 737 KB

    conv_kernel<<<dim3(NB * NPAIR), dim3(256), 0, stream>>>(x, w, G2);
    table_kernel<<<dim3(180), dim3(256), 0, stream>>>(tpr);
    bp_kernel<<<dim3(2048), dim3(256), 0, stream>>>(G2, tpr, out);
}

// Round 12
// 220.325 us; speedup vs baseline: 1.2637x; 1.2637x over previous
//
#include <hip/hip_runtime.h>
#include <math.h>

#define NB 8
#define NA 720
#define NQ 180           // angle quads {q, 719-q, 359-q, 360+q}
#define ND 1024
#define NH 512
#define NW 512

// DS = 4/1024 -> 1/DS = 256. S0 = -2 + DS/2 -> -S0/DS = 511.5
#define DXF 0.00390625f
#define IMG_MIN_F (-1.0f)
#define DTH_D (3.14159265358979323846 / 720.0)

#define TI 32            // table tile: 32 top rows
#define TJ 32            // table tile: 32 cols
#define WIN 64           // staged window elements; u_local stays in [1, ~52]

typedef unsigned int uint32;
typedef __fp16 half2v __attribute__((ext_vector_type(2)));   // matches cvt_pkrtz return

// ---------------- Kernel 1: 11-tap conv on angle QUAD -> dup-neighbor f16 G4 -------------
// G4[b][q][d] (uint4, 16B): word r = pack(y_r[d], y_r[d+1]) f16x2 for rows
// r in {q, 719-q, 359-q, 360+q}. One b128 read gives both taps of all 4 rows.
__global__ __launch_bounds__(256) void conv_kernel(const float* __restrict__ x,
                                                   const float* __restrict__ w,
                                                   uint4* __restrict__ G4) {
    int id = blockIdx.x;                  // b*180 + q
    int b = id / NQ;
    int q = id - b * NQ;
    int rows[4] = {q, 719 - q, 359 - q, 360 + q};

    __shared__ float s[4][16 + ND + 16];
    __shared__ float wk[16];

    int tid = threadIdx.x;                // 256 threads
    if (tid < 16) {
#pragma unroll
        for (int r = 0; r < 4; ++r) { s[r][tid] = 0.0f; s[r][16 + ND + tid] = 0.0f; }
    }
    if (tid < 11) wk[tid] = w[tid] * (float)DTH_D;

#pragma unroll
    for (int r = 0; r < 4; ++r) {
        const float* xr = x + ((size_t)b * NA + rows[r]) * ND;
        *(float4*)&s[r][16 + tid * 4] = ((const float4*)xr)[tid];
    }
    __syncthreads();

    int d0 = tid * 4;
    uint32 wrd[4][4];
#pragma unroll
    for (int r = 0; r < 4; ++r) {
        float o[5];
#pragma unroll
        for (int t = 0; t < 5; ++t) {
            float acc = 0.f;
#pragma unroll
            for (int k = 0; k < 11; ++k) acc = fmaf(wk[k], s[r][6 + d0 + t + k], acc);
            o[t] = acc;
        }
        union { _Float16 hf; unsigned short us; } cv;
        unsigned short h[5];
#pragma unroll
        for (int t = 0; t < 5; ++t) { cv.hf = (_Float16)o[t]; h[t] = cv.us; }
#pragma unroll
        for (int t = 0; t < 4; ++t) wrd[r][t] = (uint32)h[t] | ((uint32)h[t + 1] << 16);
    }
    uint4* gout = G4 + ((size_t)b * NQ + q) * ND + d0;
#pragma unroll
    for (int t = 0; t < 4; ++t)
        gout[t] = make_uint4(wrd[0][t], wrd[1][t], wrd[2][t], wrd[3][t]);
}

// ---------------- Kernel 2: fused per-(tile,quad) table: (ca, sa, 511.5-b1, 511.5-b2) ----
__global__ __launch_bounds__(256) void table_kernel(float4* __restrict__ tpr) {
    int idx = blockIdx.x * 256 + threadIdx.x;   // 180 quads * 128 tiles = 23040
    if (idx >= NQ * 128) return;
    int q = idx >> 7;
    int t = idx & 127;
    float th = (float)((q + 0.5) * DTH_D);      // THETAS f64->f32 like reference
    double thd = (double)th;
    float ca = (float)(cos(thd) * 256.0);
    float sa = (float)(sin(thd) * 256.0);

    int it = t >> 4, jt = t & 15;
    int ibase = it * TI, jbase = jt * TJ;
    float pi_lo = IMG_MIN_F + (ibase + 0.5f) * DXF;
    float pi_hi = IMG_MIN_F + (ibase + TI - 0.5f) * DXF;
    float pj_lo = IMG_MIN_F + (jbase + 0.5f) * DXF;
    float pj_hi = IMG_MIN_F + (jbase + TJ - 0.5f) * DXF;
    float sj = fminf(pj_lo * sa, pj_hi * sa);
    float umin1 = 511.5f + fminf(pi_lo * ca, pi_hi * ca) + sj;
    float umin2 = 511.5f + fminf(-pi_lo * ca, -pi_hi * ca) + sj;
    int b1 = ((int)floorf(umin1) - 1) & ~3;     // 4-elem align -> 64B align in G4
    int b2 = ((int)floorf(umin2) - 1) & ~3;
    b1 = max(0, min(b1, ND - WIN));
    b2 = max(0, min(b2, ND - WIN));
    tpr[(size_t)t * NQ + q] =
        make_float4(ca, sa, 511.5f - (float)b1, 511.5f - (float)b2);
}

// ---------------- Kernel 3: backprojection, 4-fold symmetry -----------------------------
// One u-group = 1 ds_read_b128 (4 rows x 2 taps) + 1 pkrtz + 4 v_dot2 = 4 samples.
// u1 -> pixels (i,j)@q, (511-i,j)@719-q, (j,i)@359-q [->PB], (511-j,i)@360+q [->PC].
// u2 -> (511-i,j)@q, (i,j)@719-q, (j,511-i)@359-q [->PB], (511-j,511-i)@360+q [->PC].
// T/M stored to out; B-partials to PB/PC (each dest pixel exactly once); combine adds.

__device__ __forceinline__ void async_ld16(const float* g, float* l) {
    __builtin_amdgcn_global_load_lds((const __attribute__((address_space(1))) void*)g,
                                     (__attribute__((address_space(3))) void*)l,
                                     16, 0, 0);
}

#define WAIT_VM0_BARRIER() do { \
    asm volatile("" ::: "memory"); \
    __builtin_amdgcn_s_waitcnt(0x0F70); /* vmcnt(0) only */ \
    __builtin_amdgcn_s_barrier(); \
    asm volatile("" ::: "memory"); \
} while (0)

// acc(f32) += taps.lo16 * gf.lo + taps.hi16 * gf.hi   (one VOP3P dot2)
#define DOT2(acc_, taps_, gf_) \
    asm("v_dot2_f32_f16 %0, %1, %2, %0" : "+v"(acc_) : "v"(taps_), "v"(gf_))

__global__ __launch_bounds__(256, 8) void bp_kernel(const uint4* __restrict__ G4,
                                                    const float4* __restrict__ tpr,
                                                    float* __restrict__ out,
                                                    float* __restrict__ PB,
                                                    float* __restrict__ PC) {
    int bid = blockIdx.x;
    // XCD-chunked swizzle (2048 = 8*256, bijective): XCD x -> all 256 blocks of batch x
    int lb = (bid & 7) * 256 + (bid >> 3);
    int b = lb >> 8;             // batch 0..7
    int t16 = lb & 255;          // 16-row x 32-col half-tile id
    int it16 = t16 >> 4;         // 0..15 over top-half rows
    int jt = t16 & 15;
    int ibase = it16 * 16, jbase = jt * 32;
    int tile32 = (it16 >> 1) * 16 + jt;      // table tile (32x32)

    int tid = threadIdx.x;
    int lane = tid & 63;
    int wv = tid >> 6;           // 0..3 -> stages quad c*4+wv
    int jj = lane & 31;
    int hi = lane >> 5;          // 0/1 -> +1 row

    int j = jbase + jj;
    float pxj = IMG_MIN_F + (j + 0.5f) * DXF;
    int i0 = ibase + 2 * wv + hi;           // +8*r, r=0..1
    float pxi = IMG_MIN_F + (i0 + 0.5f) * DXF;

    __shared__ __align__(16) uint4 buf[2][4][2][WIN];   // 2*4*2*64*16 = 16384 B

    const uint4* gp = G4 + (size_t)b * (NQ * ND);
    const float4* tp = tpr + (size_t)tile32 * NQ;

    float accT[2] = {0.f, 0.f};             // (i,j)          angles q, 719-q
    float accM[2] = {0.f, 0.f};             // (511-i,j)      angles q, 719-q
    float accB1[2] = {0.f, 0.f};            // (j,i)          angles 359-q (u1)
    float accB2[2] = {0.f, 0.f};            // (511-j,i)      angles 360+q (u1)
    float accB3[2] = {0.f, 0.f};            // (j,511-i)      angles 359-q (u2)
    float accB4[2] = {0.f, 0.f};            // (511-j,511-i)  angles 360+q (u2)

#define STAGE(c_, bs_) do { \
    int q_ = (c_) * 4 + wv; \
    float4 t4_ = tp[q_]; \
    int b1_ = (int)(511.5f - t4_.z); \
    int b2_ = (int)(511.5f - t4_.w); \
    const float* g1_ = (const float*)(gp + (size_t)q_ * ND + b1_) + lane * 4; \
    const float* g2_ = (const float*)(gp + (size_t)q_ * ND + b2_) + lane * 4; \
    async_ld16(g1_, (float*)&buf[bs_][wv][0][0]); \
    async_ld16(g2_, (float*)&buf[bs_][wv][1][0]); \
} while (0)

    STAGE(0, 0);
    WAIT_VM0_BARRIER();

    for (int c = 0; c < 45; ++c) {
        int cur = c & 1;
        if (c + 1 < 45) STAGE(c + 1, cur ^ 1);   // 2 async DMAs per wave
#pragma unroll
        for (int k = 0; k < 4; ++k) {
            float4 t4 = tp[c * 4 + k];         // uniform -> s_load_dwordx4
            float du = t4.x * (8.0f * DXF);
            float u1 = fmaf(pxj, t4.y, fmaf(pxi, t4.x, t4.z));    // local in W1
            float u2 = fmaf(pxj, t4.y, fmaf(pxi, -t4.x, t4.w));   // local in W2
            const uint4* W1 = &buf[cur][k][0][0];
            const uint4* W2 = &buf[cur][k][1][0];
#pragma unroll
            for (int r = 0; r < 2; ++r) {
                // ---- u1: words = rows {q -> T, 719-q -> M, 359-q -> B1, 360+q -> B2}
                int iu1 = (int)u1;                    // u1 in [1,52): trunc == floor
                float f1 = __builtin_amdgcn_fractf(u1);
                half2v pk1 = __builtin_amdgcn_cvt_pkrtz(1.0f - f1, f1);
                uint4 v1 = W1[iu1];                   // one ds_read_b128
                DOT2(accT[r],  v1.x, pk1);
                DOT2(accM[r],  v1.y, pk1);
                DOT2(accB1[r], v1.z, pk1);
                DOT2(accB2[r], v1.w, pk1);

                // ---- u2: words = rows {q -> M, 719-q -> T, 359-q -> B3, 360+q -> B4}
                int iu2 = (int)u2;
                float f2 = __builtin_amdgcn_fractf(u2);
                half2v pk2 = __builtin_amdgcn_cvt_pkrtz(1.0f - f2, f2);
                uint4 v2 = W2[iu2];                   // one ds_read_b128
                DOT2(accM[r],  v2.x, pk2);
                DOT2(accT[r],  v2.y, pk2);
                DOT2(accB3[r], v2.z, pk2);
                DOT2(accB4[r], v2.w, pk2);

                u1 += du;
                u2 -= du;
            }
        }
        WAIT_VM0_BARRIER();                    // drain this chunk's DMAs, swap buffers
    }

    float* orow = out + (size_t)b * (NH * NW);
    float* pbb = PB + (size_t)b * (NH * NW);
    float* pcc = PC + (size_t)b * (NH * NW);
#pragma unroll
    for (int r = 0; r < 2; ++r) {
        int i = i0 + 8 * r;
        orow[i * NW + j] = accT[r];
        orow[(511 - i) * NW + j] = accM[r];
        pbb[j * NW + i] = accB1[r];
        pbb[j * NW + (511 - i)] = accB3[r];
        pcc[(511 - j) * NW + i] = accB2[r];
        pcc[(511 - j) * NW + (511 - i)] = accB4[r];
    }
#undef STAGE
}

// ---------------- Kernel 4: out += PB + PC ----------------------------------------------
__global__ __launch_bounds__(256) void combine_kernel(float4* __restrict__ out,
                                                      const float4* __restrict__ PB,
                                                      const float4* __restrict__ PC) {
    size_t idx = (size_t)blockIdx.x * 256 + threadIdx.x;  // 2048*256 = 8*512*512/4
    float4 o = out[idx];
    float4 pb = PB[idx];
    float4 pc = PC[idx];
    o.x += pb.x + pc.x;
    o.y += pb.y + pc.y;
    o.z += pb.z + pc.z;
    o.w += pb.w + pc.w;
    out[idx] = o;
}

extern "C" void kernel_launch(void* const* d_in, const int* in_sizes, int n_in,
                              void* d_out, int out_size, void* d_ws, size_t ws_size,
                              hipStream_t stream) {
    const float* x = (const float*)d_in[0];      // [8,1,720,1024] f32
    const float* w = (const float*)d_in[1];      // [1,1,1,11] f32
    float* out = (float*)d_out;                  // [8,1,512,512] f32

    char* ws = (char*)d_ws;
    uint4* G4 = (uint4*)ws;                                  // 8*180*1024*16 = 23.6 MB
    float4* tpr = (float4*)(ws + (size_t)NB * NQ * ND * 16); // 128*180*16 = 368 KB
    float* PB = (float*)((char*)tpr + (size_t)128 * NQ * 16);
    float* PC = PB + (size_t)NB * NH * NW;                   // 8.39 MB each

    conv_kernel<<<dim3(NB * NQ), dim3(256), 0, stream>>>(x, w, G4);
    table_kernel<<<dim3(90), dim3(256), 0, stream>>>(tpr);
    bp_kernel<<<dim3(2048), dim3(256), 0, stream>>>(G4, tpr, out, PB, PC);
    combine_kernel<<<dim3(2048), dim3(256), 0, stream>>>((float4*)out,
                                                         (const float4*)PB,
                                                         (const float4*)PC);
}